// Round 2
// baseline (862.597 us; speedup 1.0000x reference)
//
#include <hip/hip_runtime.h>
#include <cstddef>

// SpectralConv2d (FNO): B=16, Cin=Cout=64, H=W=256, modes 20x20.
// Strategy: partial DFTs (only 40 ky x 20 kx modes survive), factored per axis.
//   A: W-DFT   x[B,C,H,256]        -> X1[B,C,H,20]   (complex)   [in d_out as scratch]
//   B: H-DFT   X1                  -> X2[B,C,40,20]               [ws]
//   M: mix     X2 (x) w1/w2        -> Z [B,Co,40,20]              [ws]
//   C: inv-H   Z                   -> Y [B,Co,256,20]             [ws]
//   D: inv-rfft-W  Y               -> out[B,Co,256,256]
// Twiddles: per-thread rotation recurrence, __sincosf refresh every 16 steps.
//
// R1 bug: ws offsets were computed as if X2/Z held 1,310,720 floats; actual
// complex sizes are X2=Z=819,200 float2 (1,638,400 floats) -> Z overlapped
// X2's tail and Y overlapped Z's tail, corrupting batches b>=12 (absmax
// 7.6e-4). Fixed: offsets in float2 units, disjoint regions.

constexpr float KTH = 6.28318530717958647692f / 256.0f; // 2*pi/256

// ---------------- Kernel A: partial DFT along W ----------------
// grid 4096, block 320. Each block: 64 rows (row=(b,c,h)). thread=(slot 0..15, kx 0..19),
// each thread handles 4 consecutive rows for one kx.
__global__ __launch_bounds__(320) void dft_w_kernel(const float* __restrict__ x,
                                                    float2* __restrict__ X1) {
  int tid = threadIdx.x;
  int slot = tid / 20;   // 0..15
  int kx   = tid % 20;
  size_t row0 = (size_t)blockIdx.x * 64 + (size_t)slot * 4;
  const float* xr = x + row0 * 256;

  float a0r = 0.f, a0i = 0.f, a1r = 0.f, a1i = 0.f;
  float a2r = 0.f, a2i = 0.f, a3r = 0.f, a3i = 0.f;
  // step rotation e^{-2*pi*i*kx/256} = (cr, srn)
  float cr, srn;
  __sincosf((float)kx * KTH, &srn, &cr);
  srn = -srn;

  for (int w0 = 0; w0 < 256; w0 += 16) {
    int m = (kx * w0) & 255;
    float c, s;
    __sincosf((float)m * KTH, &s, &c);
    s = -s;  // e^{-i theta}
#pragma unroll
    for (int dw = 0; dw < 16; ++dw) {
      int w = w0 + dw;
      float x0 = xr[w];
      float x1 = xr[256 + w];
      float x2 = xr[512 + w];
      float x3 = xr[768 + w];
      a0r = fmaf(x0, c, a0r); a0i = fmaf(x0, s, a0i);
      a1r = fmaf(x1, c, a1r); a1i = fmaf(x1, s, a1i);
      a2r = fmaf(x2, c, a2r); a2i = fmaf(x2, s, a2i);
      a3r = fmaf(x3, c, a3r); a3i = fmaf(x3, s, a3i);
      float cn = c * cr - s * srn;
      s = fmaf(c, srn, s * cr);
      c = cn;
    }
  }
  size_t ob = row0 * 20 + (size_t)kx;
  X1[ob]      = make_float2(a0r, a0i);
  X1[ob + 20] = make_float2(a1r, a1i);
  X1[ob + 40] = make_float2(a2r, a2i);
  X1[ob + 60] = make_float2(a3r, a3i);
}

// ---------------- Kernel B: partial DFT along H ----------------
// grid 1024 (=B*Cin), block 256. Stage X1[bc,:,:] (256x20 c64 = 40KB) in LDS,
// each thread computes up to 4 of the 800 (ky,kx) outputs.
__global__ __launch_bounds__(256) void dft_h_kernel(const float2* __restrict__ X1,
                                                    float2* __restrict__ X2) {
  __shared__ float2 Xs[256 * 20];
  int bc = blockIdx.x;
  const float2* src = X1 + (size_t)bc * (256 * 20);
  for (int i = threadIdx.x; i < 256 * 20; i += 256) Xs[i] = src[i];
  __syncthreads();

  for (int o = threadIdx.x; o < 800; o += 256) {
    int j = o / 20, kx = o % 20;
    int ky = (j < 20) ? j : 216 + j;  // 0..19 or 236..255
    float cr, srn;
    __sincosf((float)ky * KTH, &srn, &cr);
    srn = -srn;
    float ar = 0.f, ai = 0.f;
    for (int h0 = 0; h0 < 256; h0 += 16) {
      int m = (ky * h0) & 255;
      float c, s;
      __sincosf((float)m * KTH, &s, &c);
      s = -s;
#pragma unroll
      for (int dh = 0; dh < 16; ++dh) {
        float2 v = Xs[(h0 + dh) * 20 + kx];
        ar = fmaf(v.x, c, fmaf(-v.y, s, ar));
        ai = fmaf(v.x, s, fmaf(v.y, c, ai));
        float cn = c * cr - s * srn;
        s = fmaf(c, srn, s * cr);
        c = cn;
      }
    }
    X2[(size_t)bc * 800 + o] = make_float2(ar, ai);
  }
}

// ---------------- Kernel M: complex channel mixing ----------------
// grid 800 (one per (j,kx) mode), block 256. Z[b,o] = sum_i X2[b,i]*W[i,o].
__global__ __launch_bounds__(256) void mix_kernel(const float2* __restrict__ X2,
                                                  const float* __restrict__ w1r,
                                                  const float* __restrict__ w1i,
                                                  const float* __restrict__ w2r,
                                                  const float* __restrict__ w2i,
                                                  float2* __restrict__ Z) {
  __shared__ float2 Xs[16 * 64];  // [b][i]
  __shared__ float Wr[64 * 64];   // [i][o]
  __shared__ float Wi[64 * 64];
  int blk = blockIdx.x;           // j*20+kx
  int j = blk / 20, kx = blk % 20;
  const float* wr; const float* wi; int moff;
  if (j < 20) { wr = w1r; wi = w1i; moff = j * 20 + kx; }
  else        { wr = w2r; wi = w2i; moff = (j - 20) * 20 + kx; }

  for (int io = threadIdx.x; io < 4096; io += 256) {
    Wr[io] = wr[(size_t)io * 400 + moff];
    Wi[io] = wi[(size_t)io * 400 + moff];
  }
  for (int bi = threadIdx.x; bi < 1024; bi += 256) {
    Xs[bi] = X2[(size_t)bi * 800 + blk];
  }
  __syncthreads();

  int b  = threadIdx.x >> 4;         // 0..15
  int o0 = (threadIdx.x & 15) * 4;   // 0,4,...,60
  float zr[4] = {0, 0, 0, 0}, zi[4] = {0, 0, 0, 0};
  for (int i = 0; i < 64; ++i) {
    float2 xv = Xs[b * 64 + i];
#pragma unroll
    for (int q = 0; q < 4; ++q) {
      float wrv = Wr[i * 64 + o0 + q];
      float wiv = Wi[i * 64 + o0 + q];
      zr[q] = fmaf(xv.x, wrv, fmaf(-xv.y, wiv, zr[q]));
      zi[q] = fmaf(xv.x, wiv, fmaf(xv.y, wrv, zi[q]));
    }
  }
#pragma unroll
  for (int q = 0; q < 4; ++q) {
    Z[(size_t)(b * 64 + o0 + q) * 800 + blk] = make_float2(zr[q], zi[q]);
  }
}

// ---------------- Kernel C: inverse DFT along H ----------------
// grid 1024 (=B*Cout), block 256 (thread = h). Y[h,kx] = sum_j Z[j,kx] e^{+2pi i ky_j h/256}.
__global__ __launch_bounds__(256) void idft_h_kernel(const float2* __restrict__ Z,
                                                     float2* __restrict__ Y) {
  __shared__ float2 Zs[800];
  int bo = blockIdx.x;
  const float2* src = Z + (size_t)bo * 800;
  for (int i = threadIdx.x; i < 800; i += 256) Zs[i] = src[i];
  __syncthreads();

  int h = threadIdx.x;
  float cr, sr;
  __sincosf((float)h * KTH, &sr, &cr);  // step e^{+2pi i h/256}
  float accr[20], acci[20];
#pragma unroll
  for (int k = 0; k < 20; ++k) { accr[k] = 0.f; acci[k] = 0.f; }

  float c = 1.0f, s = 0.0f;  // j=0 -> ky=0
  for (int j = 0; j < 40; ++j) {
    if (j == 20) {  // jump to ky=236
      int m = (236 * h) & 255;
      __sincosf((float)m * KTH, &s, &c);
    }
#pragma unroll
    for (int k = 0; k < 20; ++k) {
      float2 z = Zs[j * 20 + k];
      accr[k] = fmaf(z.x, c, fmaf(-z.y, s, accr[k]));
      acci[k] = fmaf(z.x, s, fmaf(z.y, c, acci[k]));
    }
    float cn = c * cr - s * sr;
    s = fmaf(c, sr, s * cr);
    c = cn;
  }
  float2* dst = Y + ((size_t)bo * 256 + h) * 20;
#pragma unroll
  for (int k = 0; k < 20; ++k) dst[k] = make_float2(accr[k], acci[k]);
}

// ---------------- Kernel D: inverse rfft along W ----------------
// grid 32768 (8 rows each), block 256 (thread = w).
// out[w] = (1/65536) * (Re Y0 + 2*sum_{k=1..19} Re(Yk e^{+2pi i k w/256})); Im(Y0) ignored.
__global__ __launch_bounds__(256) void idft_w_kernel(const float2* __restrict__ Y,
                                                     float* __restrict__ out) {
  __shared__ float2 Ys[8 * 20];
  size_t row0 = (size_t)blockIdx.x * 8;
  int t = threadIdx.x;
  if (t < 160) Ys[t] = Y[row0 * 20 + t];
  __syncthreads();

  int w = t;
  float cr, sr;
  __sincosf((float)w * KTH, &sr, &cr);  // e^{+2pi i w/256}
  float acc[8];
#pragma unroll
  for (int r = 0; r < 8; ++r) acc[r] = 0.5f * Ys[r * 20].x;

  float c = cr, s = sr;  // k=1
#pragma unroll
  for (int k = 1; k < 20; ++k) {
#pragma unroll
    for (int r = 0; r < 8; ++r) {
      float2 y = Ys[r * 20 + k];
      acc[r] = fmaf(y.x, c, fmaf(-y.y, s, acc[r]));
    }
    float cn = c * cr - s * sr;
    s = fmaf(c, sr, s * cr);
    c = cn;
  }
  const float SC = 2.0f / 65536.0f;
#pragma unroll
  for (int r = 0; r < 8; ++r) {
    out[(row0 + r) * 256 + (size_t)w] = acc[r] * SC;
  }
}

extern "C" void kernel_launch(void* const* d_in, const int* in_sizes, int n_in,
                              void* d_out, int out_size, void* d_ws, size_t ws_size,
                              hipStream_t stream) {
  const float* x   = (const float*)d_in[0];
  const float* w1r = (const float*)d_in[1];
  const float* w1i = (const float*)d_in[2];
  const float* w2r = (const float*)d_in[3];
  const float* w2i = (const float*)d_in[4];
  float* out = (float*)d_out;

  // Scratch layout (float2 units, disjoint):
  //   X1 (B*Cin*H*20 = 5,242,880 c64 = 41.9MB) lives in d_out (268MB) — consumed before D overwrites.
  //   ws: X2 [0, 819200) | Z [819200, 1638400) | Y [1638400, 6881280)   = 55.05MB total
  float2* X1  = (float2*)d_out;
  float2* wsc = (float2*)d_ws;
  float2* X2  = wsc;
  float2* Zb  = wsc + 819200;    // after X2 (16*64*800 c64)
  float2* Yb  = wsc + 1638400;   // after Z  (16*64*800 c64); Y = 16*64*256*20 c64

  dft_w_kernel <<<4096, 320, 0, stream>>>(x, X1);
  dft_h_kernel <<<1024, 256, 0, stream>>>(X1, X2);
  mix_kernel   <<<800, 256, 0, stream>>>(X2, w1r, w1i, w2r, w2i, Zb);
  idft_h_kernel<<<1024, 256, 0, stream>>>(Zb, Yb);
  idft_w_kernel<<<32768, 256, 0, stream>>>(Yb, out);
}

// Round 3
// 765.467 us; speedup vs baseline: 1.1269x; 1.1269x over previous
//
#include <hip/hip_runtime.h>
#include <cstddef>

// SpectralConv2d (FNO): B=16, Cin=Cout=64, H=W=256, modes 20x20.
//   A: W-DFT   x[B,C,H,256]  -> X1[B,C,H,20]  (c64)   [d_out scratch]
//   B: H-DFT   X1            -> X2[B,C,40,20]          [ws]
//   M: mix     X2 (x) w1/w2  -> Z [B,Co,40,20]         [ws]
//   CD: inv-H + inv-rfft-W fused: Z -> out[B,Co,256,256]
// R3: A restaged through LDS (float4 global, b128 LDS, pad 132);
//     B uses (ky, kx-pair) threads + float4 LDS reads, 448-thr blocks;
//     C+D fused with Y kept in LDS (pad stride 21).

constexpr float KTH = 6.28318530717958647692f / 256.0f; // 2*pi/256

// ---------------- Kernel A: partial DFT along W ----------------
// grid 4096, block 320 (slot 0..15 x kx 0..19). Block = 64 rows; x staged in
// LDS in two 128-w chunks (pad stride 132 -> <=2-way bank conflicts = free).
// Each thread: 4 rows x 1 kx, twiddle rotation recurrence (refresh /16).
__global__ __launch_bounds__(320) void dft_w_kernel(const float* __restrict__ x,
                                                    float2* __restrict__ X1) {
  __shared__ float xs[64 * 132];  // 33.8 KB
  int tid = threadIdx.x;
  int slot = tid / 20;   // 0..15
  int kx   = tid % 20;
  size_t row0 = (size_t)blockIdx.x * 64;
  const float* xb = x + row0 * 256;

  float a0r = 0.f, a0i = 0.f, a1r = 0.f, a1i = 0.f;
  float a2r = 0.f, a2i = 0.f, a3r = 0.f, a3i = 0.f;
  float cr, srn;
  __sincosf((float)kx * KTH, &srn, &cr);
  srn = -srn;  // step e^{-2pi i kx/256}

  const float* base = xs + slot * 4 * 132;

  for (int chunk = 0; chunk < 2; ++chunk) {
    __syncthreads();  // previous chunk fully consumed
    // stage 64 rows x 128 w: 2048 float4, coalesced
    for (int i = tid; i < 2048; i += 320) {
      int r  = i >> 5;       // 32 float4 per row
      int c4 = i & 31;
      float4 v = *(const float4*)(xb + (size_t)r * 256 + chunk * 128 + c4 * 4);
      *(float4*)(xs + r * 132 + c4 * 4) = v;
    }
    __syncthreads();

    for (int w0 = 0; w0 < 128; w0 += 16) {
      int wg = chunk * 128 + w0;
      int m = (kx * wg) & 255;
      float c, s;
      __sincosf((float)m * KTH, &s, &c);
      s = -s;
#pragma unroll
      for (int dw = 0; dw < 16; dw += 4) {
        float4 v0 = *(const float4*)(base + 0 * 132 + w0 + dw);
        float4 v1 = *(const float4*)(base + 1 * 132 + w0 + dw);
        float4 v2 = *(const float4*)(base + 2 * 132 + w0 + dw);
        float4 v3 = *(const float4*)(base + 3 * 132 + w0 + dw);
#define DFTW_STEP(e)                                                  \
        {                                                             \
          a0r = fmaf(v0.e, c, a0r); a0i = fmaf(v0.e, s, a0i);         \
          a1r = fmaf(v1.e, c, a1r); a1i = fmaf(v1.e, s, a1i);         \
          a2r = fmaf(v2.e, c, a2r); a2i = fmaf(v2.e, s, a2i);         \
          a3r = fmaf(v3.e, c, a3r); a3i = fmaf(v3.e, s, a3i);         \
          float cn = c * cr - s * srn;                                \
          s = fmaf(c, srn, s * cr);                                   \
          c = cn;                                                     \
        }
        DFTW_STEP(x) DFTW_STEP(y) DFTW_STEP(z) DFTW_STEP(w)
#undef DFTW_STEP
      }
    }
  }

  size_t ob = (row0 + (size_t)slot * 4) * 20 + (size_t)kx;
  X1[ob]      = make_float2(a0r, a0i);
  X1[ob + 20] = make_float2(a1r, a1i);
  X1[ob + 40] = make_float2(a2r, a2i);
  X1[ob + 60] = make_float2(a3r, a3i);
}

// ---------------- Kernel B: partial DFT along H ----------------
// grid 1024 (=B*Cin), block 448 (7 waves): threads 0..399 = (ky_i 0..39, kx-pair 0..9).
// X1[bc] staged as float4 [h][kxpair] (natural layout, aligned b128 reads).
__global__ __launch_bounds__(448) void dft_h_kernel(const float2* __restrict__ X1,
                                                    float2* __restrict__ X2) {
  __shared__ float4 Xs4[256 * 10];  // 40 KB
  int bc = blockIdx.x;
  const float4* src = (const float4*)(X1 + (size_t)bc * 5120);
  for (int i = threadIdx.x; i < 2560; i += 448) Xs4[i] = src[i];
  __syncthreads();

  int t = threadIdx.x;
  if (t < 400) {
    int ky_i = t / 10;                        // 0..39
    int g    = t % 10;                        // kx pair -> kx = 2g, 2g+1
    int ky = (ky_i < 20) ? ky_i : 216 + ky_i; // 0..19 or 236..255
    float cr, srn;
    __sincosf((float)ky * KTH, &srn, &cr);
    srn = -srn;
    float ar0 = 0.f, ai0 = 0.f, ar1 = 0.f, ai1 = 0.f;
    for (int h0 = 0; h0 < 256; h0 += 16) {
      int m = (ky * h0) & 255;
      float c, s;
      __sincosf((float)m * KTH, &s, &c);
      s = -s;
#pragma unroll
      for (int dh = 0; dh < 16; ++dh) {
        float4 v = Xs4[(h0 + dh) * 10 + g];  // (re0, im0, re1, im1)
        ar0 = fmaf(v.x, c, fmaf(-v.y, s, ar0));
        ai0 = fmaf(v.x, s, fmaf(v.y, c, ai0));
        ar1 = fmaf(v.z, c, fmaf(-v.w, s, ar1));
        ai1 = fmaf(v.z, s, fmaf(v.w, c, ai1));
        float cn = c * cr - s * srn;
        s = fmaf(c, srn, s * cr);
        c = cn;
      }
    }
    size_t ob = (size_t)bc * 800 + (size_t)ky_i * 20 + (size_t)g * 2;
    X2[ob]     = make_float2(ar0, ai0);
    X2[ob + 1] = make_float2(ar1, ai1);
  }
}

// ---------------- Kernel M: complex channel mixing ----------------
// grid 800 (one per (j,kx) mode), block 256. Z[b,o] = sum_i X2[b,i]*W[i,o].
__global__ __launch_bounds__(256) void mix_kernel(const float2* __restrict__ X2,
                                                  const float* __restrict__ w1r,
                                                  const float* __restrict__ w1i,
                                                  const float* __restrict__ w2r,
                                                  const float* __restrict__ w2i,
                                                  float2* __restrict__ Z) {
  __shared__ float2 Xs[16 * 64];  // [b][i]
  __shared__ float Wr[64 * 64];   // [i][o]
  __shared__ float Wi[64 * 64];
  int blk = blockIdx.x;           // j*20+kx
  int j = blk / 20, kx = blk % 20;
  const float* wr; const float* wi; int moff;
  if (j < 20) { wr = w1r; wi = w1i; moff = j * 20 + kx; }
  else        { wr = w2r; wi = w2i; moff = (j - 20) * 20 + kx; }

  for (int io = threadIdx.x; io < 4096; io += 256) {
    Wr[io] = wr[(size_t)io * 400 + moff];
    Wi[io] = wi[(size_t)io * 400 + moff];
  }
  for (int bi = threadIdx.x; bi < 1024; bi += 256) {
    Xs[bi] = X2[(size_t)bi * 800 + blk];
  }
  __syncthreads();

  int b  = threadIdx.x >> 4;         // 0..15
  int o0 = (threadIdx.x & 15) * 4;   // 0,4,...,60
  float zr[4] = {0, 0, 0, 0}, zi[4] = {0, 0, 0, 0};
  for (int i = 0; i < 64; ++i) {
    float2 xv = Xs[b * 64 + i];
#pragma unroll
    for (int q = 0; q < 4; ++q) {
      float wrv = Wr[i * 64 + o0 + q];
      float wiv = Wi[i * 64 + o0 + q];
      zr[q] = fmaf(xv.x, wrv, fmaf(-xv.y, wiv, zr[q]));
      zi[q] = fmaf(xv.x, wiv, fmaf(xv.y, wrv, zi[q]));
    }
  }
#pragma unroll
  for (int q = 0; q < 4; ++q) {
    Z[(size_t)(b * 64 + o0 + q) * 800 + blk] = make_float2(zr[q], zi[q]);
  }
}

// ---------------- Kernel CD: fused inverse-H DFT + inverse rfft-W ----------------
// grid 1024 (=B*Cout), block 256. Phase2: thread=h computes Y[h,0..19] -> LDS
// (pad stride 21 -> conflict-free). Phase3: thread=w, 32 chunks of 8 h rows,
// Y reads are wave-broadcast, stores coalesced.
__global__ __launch_bounds__(256) void icd_kernel(const float2* __restrict__ Z,
                                                  float* __restrict__ out) {
  __shared__ float2 Zs[800];        // 6.4 KB
  __shared__ float2 Ys[256 * 21];   // 43 KB
  int bo = blockIdx.x;
  const float2* src = Z + (size_t)bo * 800;
  for (int i = threadIdx.x; i < 800; i += 256) Zs[i] = src[i];
  __syncthreads();

  {  // phase 2: inverse H-DFT, thread = h
    int h = threadIdx.x;
    float cr, sr;
    __sincosf((float)h * KTH, &sr, &cr);  // step e^{+2pi i h/256}
    float accr[20], acci[20];
#pragma unroll
    for (int k = 0; k < 20; ++k) { accr[k] = 0.f; acci[k] = 0.f; }
    float c = 1.0f, s = 0.0f;  // j=0 -> ky=0
    for (int j = 0; j < 40; ++j) {
      if (j == 20) {  // jump to ky=236
        int m = (236 * h) & 255;
        __sincosf((float)m * KTH, &s, &c);
      }
#pragma unroll
      for (int k = 0; k < 20; ++k) {
        float2 z = Zs[j * 20 + k];
        accr[k] = fmaf(z.x, c, fmaf(-z.y, s, accr[k]));
        acci[k] = fmaf(z.x, s, fmaf(z.y, c, acci[k]));
      }
      float cn = c * cr - s * sr;
      s = fmaf(c, sr, s * cr);
      c = cn;
    }
    float2* yrow = Ys + h * 21;
#pragma unroll
    for (int k = 0; k < 20; ++k) yrow[k] = make_float2(accr[k], acci[k]);
  }
  __syncthreads();

  // phase 3: inverse rfft along W, thread = w
  int w = threadIdx.x;
  float cr, sr;
  __sincosf((float)w * KTH, &sr, &cr);  // e^{+2pi i w/256}
  float* outb = out + (size_t)bo * 65536;
  const float SC = 2.0f / 65536.0f;
  for (int h0 = 0; h0 < 256; h0 += 8) {
    float acc[8];
#pragma unroll
    for (int r = 0; r < 8; ++r) acc[r] = 0.5f * Ys[(h0 + r) * 21].x;
    float c = cr, s = sr;  // k=1
#pragma unroll
    for (int k = 1; k < 20; ++k) {
#pragma unroll
      for (int r = 0; r < 8; ++r) {
        float2 y = Ys[(h0 + r) * 21 + k];
        acc[r] = fmaf(y.x, c, fmaf(-y.y, s, acc[r]));
      }
      float cn = c * cr - s * sr;
      s = fmaf(c, sr, s * cr);
      c = cn;
    }
#pragma unroll
    for (int r = 0; r < 8; ++r) {
      outb[(h0 + r) * 256 + w] = acc[r] * SC;
    }
  }
}

extern "C" void kernel_launch(void* const* d_in, const int* in_sizes, int n_in,
                              void* d_out, int out_size, void* d_ws, size_t ws_size,
                              hipStream_t stream) {
  const float* x   = (const float*)d_in[0];
  const float* w1r = (const float*)d_in[1];
  const float* w1i = (const float*)d_in[2];
  const float* w2r = (const float*)d_in[3];
  const float* w2i = (const float*)d_in[4];
  float* out = (float*)d_out;

  // Scratch: X1 (5,242,880 c64 = 41.9MB) in d_out (overwritten later by CD's
  // out writes — X1 consumed by B before M/CD run). ws: X2 | Z (float2 units).
  float2* X1  = (float2*)d_out;
  float2* wsc = (float2*)d_ws;
  float2* X2  = wsc;
  float2* Zb  = wsc + 819200;  // after X2 (16*64*800 c64)

  dft_w_kernel<<<4096, 320, 0, stream>>>(x, X1);
  dft_h_kernel<<<1024, 448, 0, stream>>>(X1, X2);
  mix_kernel  <<<800, 256, 0, stream>>>(X2, w1r, w1i, w2r, w2i, Zb);
  icd_kernel  <<<1024, 256, 0, stream>>>(Zb, out);
}